// Round 13
// baseline (279.325 us; speedup 1.0000x reference)
//
#include <hip/hip_runtime.h>
#include <hip/hip_bf16.h>

typedef __attribute__((ext_vector_type(4))) float  f32x4;
typedef __attribute__((ext_vector_type(8))) __bf16 bf16x8;
typedef __attribute__((ext_vector_type(8))) short  short8;

#define KDIM 4096
#define NDIM 4096
#define BK   32
#define NT   (KDIM / BK)     // 128 K-tiles

__device__ inline unsigned short f2bf(float f) {
    union { float f; unsigned u; } v; v.f = f;
    unsigned r = v.u + 0x7fffu + ((v.u >> 16) & 1u);   // RNE
    return (unsigned short)(r >> 16);
}

// ---------- kernel 1: fused prep (dequant W + cvt x), block-uniform split ----
__global__ void prep(const int* __restrict__ wq, const float* __restrict__ absmax,
                     const float* __restrict__ code, short* __restrict__ wout,
                     const float* __restrict__ xin, short* __restrict__ xout,
                     int nwblocks) {
    __shared__ float cs[256];
    cs[threadIdx.x] = code[threadIdx.x];
    __syncthreads();
    if (blockIdx.x < (unsigned)nwblocks) {
        size_t idx = ((size_t)blockIdx.x * blockDim.x + threadIdx.x) * 8;
        float am = absmax[idx >> 12];                  // BLOCKSIZE = 4096
        int4 q0 = *(const int4*)(wq + idx);
        int4 q1 = *(const int4*)(wq + idx + 4);
        short8 r;
        r[0] = (short)f2bf(cs[q0.x] * am);
        r[1] = (short)f2bf(cs[q0.y] * am);
        r[2] = (short)f2bf(cs[q0.z] * am);
        r[3] = (short)f2bf(cs[q0.w] * am);
        r[4] = (short)f2bf(cs[q1.x] * am);
        r[5] = (short)f2bf(cs[q1.y] * am);
        r[6] = (short)f2bf(cs[q1.z] * am);
        r[7] = (short)f2bf(cs[q1.w] * am);
        *(short8*)(wout + idx) = r;
    } else {
        size_t idx = ((size_t)(blockIdx.x - nwblocks) * blockDim.x + threadIdx.x) * 8;
        float4 a = *(const float4*)(xin + idx);
        float4 b = *(const float4*)(xin + idx + 4);
        short8 r;
        r[0] = (short)f2bf(a.x); r[1] = (short)f2bf(a.y);
        r[2] = (short)f2bf(a.z); r[3] = (short)f2bf(a.w);
        r[4] = (short)f2bf(b.x); r[5] = (short)f2bf(b.y);
        r[6] = (short)f2bf(b.z); r[7] = (short)f2bf(b.w);
        *(short8*)(xout + idx) = r;
    }
}

// ---------- kernel 2: 256x256 GEMM, BK=32, 4-buf uniform phases -------------
// C = A[M,K] * B[N,K]^T + bias.  8 waves; per phase (= one K=32 tile) every
// wave computes its full 128x64 output piece: 12 ds_read_b128 (4 B + 8 A)
// + stage tile t+3 (4 gload_lds) -> 32 MFMA (compiler-counted lgkm; rg-outer
// so each 4-MFMA group is unlocked by one more A-read) -> vmcnt(8) -> bar.
// LDS: 4 bufs x (A[256][32] + B[256][32]) bf16 = 128 KiB, 3-tile staging lead.
// Swizzle (R7-measured 0-conflict, 64-B rows): S'(d) = ((d>>7)&3)<<4;
// linear gload_lds dest + source pre-XORed with S'; ds_read at d ^ S'(d).
// RAW: vmcnt(8) at phase t drains tile t+1 (staged at t-2) before its reads.
// WAR: buf (t+3)&3 last read in phase t-1, staged after phase t-1's barrier.
__global__ __launch_bounds__(512, 2) void gemm256(
    const short* __restrict__ A, const short* __restrict__ Bm,
    const float* __restrict__ bias, float* __restrict__ C, int M) {

    __shared__ __attribute__((aligned(128))) char lds[131072];

    const int tid  = threadIdx.x;
    const int wid  = tid >> 6;
    const int lane = tid & 63;
    const int wr   = wid >> 2;        // 0..1 : 64-row piece within quadrant
    const int wc   = wid & 3;         // 0..3 : 32-col piece within quadrant
    const int lr   = lane & 15;
    const int kl2  = (lane >> 4) * 16;   // k fragment byte offset

    // XCD-aware chunked swizzle (512 wg, %8==0 -> bijective)
    const int nwg  = gridDim.x;
    const int cpx  = nwg >> 3;
    const int swzb = (blockIdx.x & 7) * cpx + (blockIdx.x >> 3);
    const int bx   = swzb & 15;              // NDIM/256 = 16 tiles, fastest
    const int by   = swzb >> 4;
    const int tileM = by * 256, tileN = bx * 256;

    // ---- read addressing (region-relative, 64-B rows): addr bits 7-8 = row
    // bits 1-2 = lr bits 1-2 -> kb spreads consecutive-8 lanes over 8 slots
    const int kb    = kl2 ^ (((lr >> 1) & 3) << 4);
    const int aBase = (wr * 64 + lr) * 64 + kb;    // + qr*8192 + mi*1024
    const int bBase = (wc * 32 + lr) * 64 + kb;    // + qc*8192 + ni*1024

    // ---- staging: linear LDS dest (tid*16), source pre-XORed with S'
    const int u0 = (tid * 16) ^ (((tid >> 3) & 3) << 4);          // [0, 8192)
    const int u1 = (8192 + tid * 16) ^ (((tid >> 3) & 3) << 4);   // [8192, 16384)
    const int srow0 = u0 >> 6, scol0 = (u0 & 63) >> 1;   // rows 0..127
    const int srow1 = u1 >> 6, scol1 = (u1 & 63) >> 1;   // rows 128..255

    const short* pA0 = A  + (size_t)(tileM + srow0) * KDIM + scol0;
    const short* pA1 = A  + (size_t)(tileM + srow1) * KDIM + scol1;
    const short* pB0 = Bm + (size_t)(tileN + srow0) * KDIM + scol0;
    const short* pB1 = Bm + (size_t)(tileN + srow1) * KDIM + scol1;

#define GL(SRC, DST) __builtin_amdgcn_global_load_lds(                         \
    (const __attribute__((address_space(1))) void*)(SRC),                      \
    (__attribute__((address_space(3))) void*)(DST), 16, 0, 0)

    // stage K-tile at element offset KT into buffer B_ (4 gloads)
#define STG(B_, KT) do {                                                       \
    char* _d = lds + (B_) * 32768 + tid * 16;                                  \
    GL(pA0 + (KT), _d);                                                        \
    GL(pA1 + (KT), _d + 8192);                                                 \
    GL(pB0 + (KT), _d + 16384);                                                \
    GL(pB1 + (KT), _d + 24576);                                                \
} while (0)

    f32x4  acc[8][4] = {};     // [rg][cg]; rg = qr*4+mi, cg = qc*2+ni
    bf16x8 aF[8], bF[4];

    // B-reads first (4), then A (8): first MFMA needs bF[0..3] + aF[0] = 5
    // reads; each later 4-MFMA group unlocked by one more aF read.
#define RD(B_) do {                                                            \
    const char* _b = lds + (B_) * 32768;                                       \
    _Pragma("unroll") for (int cg = 0; cg < 4; ++cg)                           \
        bF[cg] = *(const bf16x8*)(_b + 16384 + (cg >> 1) * 8192               \
                                   + (cg & 1) * 1024 + bBase);                 \
    _Pragma("unroll") for (int rg = 0; rg < 8; ++rg)                           \
        aF[rg] = *(const bf16x8*)(_b + (rg >> 2) * 8192                        \
                                   + (rg & 3) * 1024 + aBase);                 \
} while (0)

#define MFMA32() do {                                                          \
    __builtin_amdgcn_s_setprio(1);                                             \
    _Pragma("unroll") for (int rg = 0; rg < 8; ++rg)                           \
    _Pragma("unroll") for (int cg = 0; cg < 4; ++cg)                           \
        acc[rg][cg] = __builtin_amdgcn_mfma_f32_16x16x32_bf16(                 \
            aF[rg], bF[cg], acc[rg][cg], 0, 0, 0);                             \
    __builtin_amdgcn_s_setprio(0);                                             \
} while (0)

#define BAR() __builtin_amdgcn_s_barrier()

    // phase: read buf B_, stage tile at offset KT (if >=0), MFMA, counted wait
#define PH(B_, KT, VMN) do {                                                   \
    RD(B_);                                                                    \
    if ((KT) >= 0) STG(((B_) + 3) & 3, KT);                                    \
    MFMA32();                                                                  \
    if ((VMN) == 8)      asm volatile("s_waitcnt vmcnt(8)" ::: "memory");      \
    else if ((VMN) == 4) asm volatile("s_waitcnt vmcnt(4)" ::: "memory");      \
    else if ((VMN) == 0) asm volatile("s_waitcnt vmcnt(0)" ::: "memory");      \
    BAR();                                                                     \
} while (0)

    // ---- prologue: stage tiles 0,1,2 into bufs 0,1,2
    STG(0, 0);
    STG(1, BK);
    STG(2, 2 * BK);
    asm volatile("s_waitcnt vmcnt(8)" ::: "memory");   // tile 0 landed
    BAR();

    // ---- main loop: 31 iterations x 4 tiles (t = 4*it .. 4*it+3)
    for (int it = 0; it < NT / 4 - 1; ++it) {
        const int t4 = 4 * it;
        PH(0, (t4 + 3) * BK, 8);
        PH(1, (t4 + 4) * BK, 8);
        PH(2, (t4 + 5) * BK, 8);
        PH(3, (t4 + 6) * BK, 8);
    }
    // ---- tail: tiles 124..127
    PH(0, (NT - 1) * BK, 8);   // t=124: stages tile 127 into buf 3
    PH(1, -1, 4);              // t=125: tile 126 landed
    PH(2, -1, 0);              // t=126: tile 127 landed
    PH(3, -1, -1);             // t=127

    // ---- epilogue: C/D layout col = lane&15, row = (lane>>4)*4 + reg
    const int r4 = (lane >> 4) * 4;
    float bv[4];
    #pragma unroll
    for (int cg = 0; cg < 4; ++cg)
        bv[cg] = bias[tileN + (cg >> 1) * 128 + wc * 32 + (cg & 1) * 16 + lr];

    #pragma unroll
    for (int rg = 0; rg < 8; ++rg)
    #pragma unroll
    for (int cg = 0; cg < 4; ++cg) {
        const int row0 = tileM + (rg >> 2) * 128 + wr * 64 + (rg & 3) * 16 + r4;
        const int col  = tileN + (cg >> 1) * 128 + wc * 32 + (cg & 1) * 16 + lr;
        f32x4 v = acc[rg][cg];
        #pragma unroll
        for (int j = 0; j < 4; ++j)
            C[(size_t)(row0 + j) * NDIM + col] = v[j] + bv[cg];
    }
}

extern "C" void kernel_launch(void* const* d_in, const int* in_sizes, int n_in,
                              void* d_out, int out_size, void* d_ws, size_t ws_size,
                              hipStream_t stream) {
    const float* x      = (const float*)d_in[0];
    const int*   wq     = (const int*)  d_in[1];
    const float* absmax = (const float*)d_in[2];
    const float* code   = (const float*)d_in[3];
    const float* bias   = (const float*)d_in[4];
    float* out = (float*)d_out;

    const int K = KDIM, N = NDIM;
    const int M = in_sizes[0] / K;            // 8192

    short* wbf = (short*)d_ws;                // [N][K] bf16: 32 MiB
    short* xbf = wbf + (size_t)N * K;         // [M][K] bf16: 64 MiB

    const int nwblocks = (N * K / 8) / 256;            // 8192 (exact)
    const int nxblocks = (int)((size_t)M * K / 8 / 256);
    prep<<<nwblocks + nxblocks, 256, 0, stream>>>(wq, absmax, code, wbf, x, xbf, nwblocks);

    const int nwg = (M / 256) * (N / 256);    // 512, %8 == 0
    gemm256<<<nwg, 512, 0, stream>>>(xbf, wbf, bias, out, M);
}